// Round 17
// baseline (444.681 us; speedup 1.0000x reference)
//
#include <hip/hip_runtime.h>
#include <hip/hip_bf16.h>

#define N_NODES 50000
#define N_EDGES 800000
#define HID 128
#define NBUCKET 1024
#define N_NODE_BLOCKS ((N_NODES + 255) / 256)  // 196

typedef __attribute__((ext_vector_type(8))) short bf16x8;
typedef __attribute__((ext_vector_type(4))) float f32x4;

__device__ __forceinline__ ushort f2bf(float f) {
    uint u = __float_as_uint(f);
    return (ushort)((u + 0x7FFFu + ((u >> 16) & 1u)) >> 16);  // RNE
}
__device__ __forceinline__ float bf2f(ushort h) { return __uint_as_float(((uint)h) << 16); }

// ---------------- degree count ----------------
__global__ void k_count(const int* __restrict__ ei, int* cnt) {
    int e = blockIdx.x * blockDim.x + threadIdx.x;
    if (e < N_EDGES) atomicAdd(&cnt[ei[N_EDGES + e]], 1);
}

// ---------------- counting sort by degree: per-block hist + global base ----------------
__global__ __launch_bounds__(256) void k_bhist(const int* __restrict__ cnt, int* gHist,
                                               int* __restrict__ blockBase) {
    __shared__ int lh[NBUCKET];
    int t = threadIdx.x;
    for (int d = t; d < NBUCKET; d += 256) lh[d] = 0;
    __syncthreads();
    int n = blockIdx.x * 256 + t;
    if (n < N_NODES) {
        int deg = min(cnt[n], NBUCKET - 1);
        atomicAdd(&lh[deg], 1);
    }
    __syncthreads();
    for (int d = t; d < NBUCKET; d += 256) {
        int c = lh[d];
        blockBase[blockIdx.x * NBUCKET + d] = c ? atomicAdd(&gHist[d], c) : 0;
    }
}

// exclusive prefix over gHist (node base) and gHist[d]*d (edge base)
__global__ __launch_bounds__(NBUCKET) void k_prefix(const int* __restrict__ gHist,
                                                    int* __restrict__ histBase,
                                                    int* __restrict__ edgeBase,
                                                    int* __restrict__ rowStartP) {
    __shared__ int a[NBUCKET];
    __shared__ int b[NBUCKET];
    int t = threadIdx.x;
    int h = gHist[t];
    a[t] = h;
    b[t] = h * t;
    __syncthreads();
    for (int off = 1; off < NBUCKET; off <<= 1) {
        int av = (t >= off) ? a[t - off] : 0;
        int bv = (t >= off) ? b[t - off] : 0;
        __syncthreads();
        a[t] += av;
        b[t] += bv;
        __syncthreads();
    }
    histBase[t] = a[t] - h;          // exclusive
    edgeBase[t] = b[t] - h * t;
    if (t == 0) rowStartP[N_NODES] = N_EDGES;
}

// rank[n], invRank[r], rowStartP[r] (closed form), dinvP[r]
__global__ __launch_bounds__(256) void k_rank(const int* __restrict__ cnt,
                                              const int* __restrict__ histBase,
                                              const int* __restrict__ edgeBase,
                                              const int* __restrict__ blockBase,
                                              int* __restrict__ rank,
                                              int* __restrict__ invRank,
                                              int* __restrict__ rowStartP,
                                              float* __restrict__ dinvP) {
    __shared__ int cur[NBUCKET];
    int t = threadIdx.x;
    for (int d = t; d < NBUCKET; d += 256) cur[d] = 0;
    __syncthreads();
    int n = blockIdx.x * 256 + t;
    if (n < N_NODES) {
        int deg = min(cnt[n], NBUCKET - 1);
        int slot = atomicAdd(&cur[deg], 1);
        int r = histBase[deg] + blockBase[blockIdx.x * NBUCKET + deg] + slot;
        rank[n] = r;
        invRank[r] = n;
        rowStartP[r] = edgeBase[deg] + (r - histBase[deg]) * deg;
        dinvP[r] = rsqrtf(1.0f + (float)deg);
    }
}

// csrE[pos] = {rank[src], edge_id} grouped by rank[dst]
__global__ void k_fill(const int* __restrict__ ei, const int* __restrict__ rank,
                       const int* __restrict__ rowStartP, int* cursorP,
                       int2* __restrict__ csrE) {
    int e = blockIdx.x * blockDim.x + threadIdx.x;
    if (e < N_EDGES) {
        int s = ei[e];
        int d = ei[N_EDGES + e];
        int rd = rank[d];
        int pos = rowStartP[rd] + atomicAdd(&cursorP[rd], 1);
        csrE[pos] = make_int2(rank[s], e);
    }
}

// ---------------- 5x weight transpose + bf16 hi/lo split ----------------
struct WSplitArgs {
    const float* src[5];
    ushort* th[5];
    ushort* tl[5];
};

__global__ void k_tsplit5(WSplitArgs a) {
    int i = blockIdx.x * 256 + threadIdx.x;  // 5 * 16384
    int which = i >> 14, r = i & 16383;
    int k = r >> 7, j = r & 127;
    float v = a.src[which][r];
    ushort hi = f2bf(v);
    a.th[which][j * 128 + k] = hi;
    a.tl[which][j * 128 + k] = f2bf(v - bf2f(hi));
}

// ---------------- fused encoder + layer-1 GEMM ----------------
__global__ __launch_bounds__(512, 8) void k_enc_gemm(
    const float* __restrict__ x, const float* __restrict__ Wenc,
    const float* __restrict__ benc, const int* __restrict__ invRank,
    const float* __restrict__ dinvP,
    const ushort* __restrict__ BTH, const ushort* __restrict__ BTL,
    float* __restrict__ out) {
    __shared__ uint AsH[16][68];
    __shared__ uint AsL[16][68];
    int tid = threadIdx.x;

    if (tid < 256) {
        int ln = tid >> 4, li = tid & 15;
        int r = blockIdx.x * 16 + ln;
        int n = invRank[r];
        float4 xv = *(const float4*)(x + (size_t)n * 4);
        int j0 = li * 8;
        uint uh[4], ul[4];
#pragma unroll
        for (int p = 0; p < 4; ++p) {
            ushort hs[2], ls[2];
#pragma unroll
            for (int q = 0; q < 2; ++q) {
                int j = j0 + p * 2 + q;
                float acc = benc[j];
                acc += xv.x * Wenc[0 * 128 + j];
                acc += xv.y * Wenc[1 * 128 + j];
                acc += xv.z * Wenc[2 * 128 + j];
                acc += xv.w * Wenc[3 * 128 + j];
                float v = fmaxf(acc, 0.f);
                hs[q] = f2bf(v);
                ls[q] = f2bf(v - bf2f(hs[q]));
            }
            uh[p] = (uint)hs[0] | ((uint)hs[1] << 16);
            ul[p] = (uint)ls[0] | ((uint)ls[1] << 16);
        }
        *(uint4*)&AsH[ln][li * 4] = make_uint4(uh[0], uh[1], uh[2], uh[3]);
        *(uint4*)&AsL[ln][li * 4] = make_uint4(ul[0], ul[1], ul[2], ul[3]);
    }
    __syncthreads();

    int w = tid >> 6, l = tid & 63;
    int ln = l & 15, lk = l >> 4;
    int ct = w;
    int node = blockIdx.x * 16 + ln;
    f32x4 acc = {};
#pragma unroll
    for (int kc = 0; kc < 4; ++kc) {
        uint4 uhv = *(uint4*)&AsH[ln][kc * 16 + lk * 4];
        uint4 ulv = *(uint4*)&AsL[ln][kc * 16 + lk * 4];
        bf16x8 hh, hl;
        __builtin_memcpy(&hh, &uhv, 16);
        __builtin_memcpy(&hl, &ulv, 16);
        size_t boff = (size_t)(ct * 16 + ln) * 128 + kc * 32 + lk * 8;
        bf16x8 wh = *(const bf16x8*)(BTH + boff);
        bf16x8 wl = *(const bf16x8*)(BTL + boff);
        acc = __builtin_amdgcn_mfma_f32_16x16x32_bf16(wh, hh, acc, 0, 0, 0);
        acc = __builtin_amdgcn_mfma_f32_16x16x32_bf16(wl, hh, acc, 0, 0, 0);
        acc = __builtin_amdgcn_mfma_f32_16x16x32_bf16(wh, hl, acc, 0, 0, 0);
    }
    int jb = ct * 16 + lk * 4;
    float s = dinvP[node];
    *(float4*)(out + (size_t)node * 128 + jb) =
        make_float4(acc[0] * s, acc[1] * s, acc[2] * s, acc[3] * s);
}

// ---------------- fused aggregate + GEMM (64-node tiles, degree-balanced) ----------------
// Phase A: 64 rank-consecutive nodes per block (degrees differ <=1). Each wave
// handles 8 nodes: 2 concurrently (2 groups x 16 lanes per node, full 512B row
// per group, 1-ahead prefetch) x 4 serially (degree-identical, no divergence).
// Phase B: GEMM from LDS ([64][68] padded): wave w owns col-tile ct=w, computes
// all 4 row-tiles per weight fragment -> quartered weight traffic. Dual-weight
// (last layer) runs as two sequential passes to cap register pressure.
__global__ __launch_bounds__(512, 8) void k_agg_gemm(
    const float* __restrict__ hw, const float* __restrict__ bg,
    const float* __restrict__ dinvP, const int* __restrict__ rowStartP,
    const int2* __restrict__ csrE,
    const ushort* __restrict__ BTH1, const ushort* __restrict__ BTL1,
    const ushort* __restrict__ BTH2, const ushort* __restrict__ BTL2,
    float* __restrict__ out1, float* __restrict__ out2,
    const float* __restrict__ b1, const float* __restrict__ outScale) {
    __shared__ uint AsH[64][68];
    __shared__ uint AsL[64][68];
    int tid = threadIdx.x;
    int w = tid >> 6, l = tid & 63;
    int sub = l >> 5;        // node within wave pair (concurrent)
    int g2 = (l >> 4) & 1;   // edge-group within node
    int li = l & 15;
    int c8 = li * 8;

    // ---- Phase A: 4 serial x 2 concurrent nodes per wave ----
#pragma unroll
    for (int q = 0; q < 4; ++q) {
        int r = w * 8 + sub * 4 + q;
        int n = blockIdx.x * 64 + r;
        if (n >= N_NODES) n = N_NODES - 1;  // tail clamp (stores guarded in phase B)
        float4 aA, aB;
        if (g2 == 0) {  // self term
            aA = *(const float4*)(hw + (size_t)n * 128 + c8);
            aB = *(const float4*)(hw + (size_t)n * 128 + c8 + 4);
        } else {
            aA = make_float4(0.f, 0.f, 0.f, 0.f);
            aB = aA;
        }
        int s0 = rowStartP[n], s1 = rowStartP[n + 1];
        int k = s0 + g2;
        float4 v0a = make_float4(0.f, 0.f, 0.f, 0.f), v0b = v0a;
        if (k < s1) {
            const float* rp = hw + (size_t)csrE[k].x * 128 + c8;
            v0a = *(const float4*)(rp);
            v0b = *(const float4*)(rp + 4);
        }
        for (; k < s1; k += 2) {
            float4 v1a = make_float4(0.f, 0.f, 0.f, 0.f), v1b = v1a;
            if (k + 2 < s1) {
                const float* rp = hw + (size_t)csrE[k + 2].x * 128 + c8;
                v1a = *(const float4*)(rp);
                v1b = *(const float4*)(rp + 4);
            }
            aA.x += v0a.x; aA.y += v0a.y; aA.z += v0a.z; aA.w += v0a.w;
            aB.x += v0b.x; aB.y += v0b.y; aB.z += v0b.z; aB.w += v0b.w;
            v0a = v1a;
            v0b = v1b;
        }
        // combine the 2 edge-groups (lanes l and l^16)
        aA.x += __shfl_xor(aA.x, 16); aA.y += __shfl_xor(aA.y, 16);
        aA.z += __shfl_xor(aA.z, 16); aA.w += __shfl_xor(aA.w, 16);
        aB.x += __shfl_xor(aB.x, 16); aB.y += __shfl_xor(aB.y, 16);
        aB.z += __shfl_xor(aB.z, 16); aB.w += __shfl_xor(aB.w, 16);

        if (g2 == 0) {
            float di = dinvP[n];
            float4 bbA = *(const float4*)(bg + c8);
            float4 bbB = *(const float4*)(bg + c8 + 4);
            float f0 = fmaxf(bbA.x + di * aA.x, 0.f);
            float f1 = fmaxf(bbA.y + di * aA.y, 0.f);
            float f2 = fmaxf(bbA.z + di * aA.z, 0.f);
            float f3 = fmaxf(bbA.w + di * aA.w, 0.f);
            float f4 = fmaxf(bbB.x + di * aB.x, 0.f);
            float f5 = fmaxf(bbB.y + di * aB.y, 0.f);
            float f6 = fmaxf(bbB.z + di * aB.z, 0.f);
            float f7 = fmaxf(bbB.w + di * aB.w, 0.f);
            ushort h0 = f2bf(f0), h1 = f2bf(f1), h2 = f2bf(f2), h3 = f2bf(f3);
            ushort h4 = f2bf(f4), h5 = f2bf(f5), h6 = f2bf(f6), h7 = f2bf(f7);
            uint4 uh = make_uint4((uint)h0 | ((uint)h1 << 16), (uint)h2 | ((uint)h3 << 16),
                                  (uint)h4 | ((uint)h5 << 16), (uint)h6 | ((uint)h7 << 16));
            ushort l0 = f2bf(f0 - bf2f(h0)), l1 = f2bf(f1 - bf2f(h1));
            ushort l2 = f2bf(f2 - bf2f(h2)), l3 = f2bf(f3 - bf2f(h3));
            ushort l4 = f2bf(f4 - bf2f(h4)), l5 = f2bf(f5 - bf2f(h5));
            ushort l6 = f2bf(f6 - bf2f(h6)), l7 = f2bf(f7 - bf2f(h7));
            uint4 ul = make_uint4((uint)l0 | ((uint)l1 << 16), (uint)l2 | ((uint)l3 << 16),
                                  (uint)l4 | ((uint)l5 << 16), (uint)l6 | ((uint)l7 << 16));
            *(uint4*)&AsH[r][li * 4] = uh;
            *(uint4*)&AsL[r][li * 4] = ul;
        }
    }
    __syncthreads();

    // ---- Phase B: GEMM from LDS. wave w owns col-tile ct=w; 4 row-tiles;
    //      two sequential passes for the dual-weight (last) layer ----
    int ln = l & 15, lk = l >> 4;
    int ct = w;
    int jb = ct * 16 + lk * 4;
#pragma unroll 1
    for (int set = 0; set < 2; ++set) {
        if (set && !BTH2) break;
        const ushort* TH = set ? BTH2 : BTH1;
        const ushort* TL = set ? BTL2 : BTL1;
        f32x4 acc[4] = {};
#pragma unroll
        for (int kc = 0; kc < 4; ++kc) {
            size_t boff = (size_t)(ct * 16 + ln) * 128 + kc * 32 + lk * 8;
            bf16x8 wh = *(const bf16x8*)(TH + boff);
            bf16x8 wl = *(const bf16x8*)(TL + boff);
#pragma unroll
            for (int rt = 0; rt < 4; ++rt) {
                uint4 uhv = *(uint4*)&AsH[rt * 16 + ln][kc * 16 + lk * 4];
                uint4 ulv = *(uint4*)&AsL[rt * 16 + ln][kc * 16 + lk * 4];
                bf16x8 hh, hl;
                __builtin_memcpy(&hh, &uhv, 16);
                __builtin_memcpy(&hl, &ulv, 16);
                acc[rt] = __builtin_amdgcn_mfma_f32_16x16x32_bf16(wh, hh, acc[rt], 0, 0, 0);
                acc[rt] = __builtin_amdgcn_mfma_f32_16x16x32_bf16(wl, hh, acc[rt], 0, 0, 0);
                acc[rt] = __builtin_amdgcn_mfma_f32_16x16x32_bf16(wh, hl, acc[rt], 0, 0, 0);
            }
        }
#pragma unroll
        for (int rt = 0; rt < 4; ++rt) {
            int node = blockIdx.x * 64 + rt * 16 + ln;
            if (node >= N_NODES) continue;
            if (outScale) {
                float s = outScale[node];
                *(float4*)(out1 + (size_t)node * 128 + jb) =
                    make_float4(acc[rt][0] * s, acc[rt][1] * s, acc[rt][2] * s, acc[rt][3] * s);
            } else if (set == 0) {
                *(float4*)(out1 + (size_t)node * 128 + jb) =
                    make_float4(acc[rt][0], acc[rt][1], acc[rt][2], acc[rt][3]);
            } else {
                float4 bv = *(const float4*)(b1 + jb);
                *(float4*)(out2 + (size_t)node * 128 + jb) =
                    make_float4(acc[rt][0] + bv.x, acc[rt][1] + bv.y,
                                acc[rt][2] + bv.z, acc[rt][3] + bv.w);
            }
        }
    }
}

// ---------------- edge final: out[eid] = relu(P[rs] + Qb[rd]) @ W2 + b2 ----------------
__global__ __launch_bounds__(256) void k_edge_final(const float* __restrict__ P,
                                                    const float* __restrict__ Qb,
                                                    const int* __restrict__ rowStartP,
                                                    const int2* __restrict__ csrE,
                                                    const float* __restrict__ W2,
                                                    const float* __restrict__ b2,
                                                    float* __restrict__ out) {
    int wid = (blockIdx.x * 256 + threadIdx.x) >> 6;  // one wave per dst rank
    int l = threadIdx.x & 63;
    if (wid >= N_NODES) return;
    int s0 = rowStartP[wid], s1 = rowStartP[wid + 1];
    if (s0 >= s1) return;
    int j8 = (l & 15) * 8;
    int g = l >> 4;

    float4 qa = *(const float4*)(Qb + (size_t)wid * 128 + j8);
    float4 qb = *(const float4*)(Qb + (size_t)wid * 128 + j8 + 4);
    float w2r[8][3];
#pragma unroll
    for (int k = 0; k < 8; ++k) {
        w2r[k][0] = W2[(j8 + k) * 3 + 0];
        w2r[k][1] = W2[(j8 + k) * 3 + 1];
        w2r[k][2] = W2[(j8 + k) * 3 + 2];
    }
    float bz0 = b2[0], bz1 = b2[1], bz2 = b2[2];

    int k = s0 + g;
    int2 c = make_int2(0, 0);
    float4 pa = make_float4(0.f, 0.f, 0.f, 0.f), pb = pa;
    if (k < s1) {
        c = csrE[k];
        const float* pr = P + (size_t)c.x * 128 + j8;
        pa = *(const float4*)(pr);
        pb = *(const float4*)(pr + 4);
    }
    for (; k < s1; k += 4) {
        int kn = k + 4;
        int2 cn = make_int2(0, 0);
        float4 pan = make_float4(0.f, 0.f, 0.f, 0.f), pbn = pan;
        if (kn < s1) {
            cn = csrE[kn];
            const float* prn = P + (size_t)cn.x * 128 + j8;
            pan = *(const float4*)(prn);
            pbn = *(const float4*)(prn + 4);
        }
        float z[8];
        z[0] = fmaxf(pa.x + qa.x, 0.f);
        z[1] = fmaxf(pa.y + qa.y, 0.f);
        z[2] = fmaxf(pa.z + qa.z, 0.f);
        z[3] = fmaxf(pa.w + qa.w, 0.f);
        z[4] = fmaxf(pb.x + qb.x, 0.f);
        z[5] = fmaxf(pb.y + qb.y, 0.f);
        z[6] = fmaxf(pb.z + qb.z, 0.f);
        z[7] = fmaxf(pb.w + qb.w, 0.f);
        float o0 = 0.f, o1 = 0.f, o2 = 0.f;
#pragma unroll
        for (int q = 0; q < 8; ++q) {
            o0 += z[q] * w2r[q][0];
            o1 += z[q] * w2r[q][1];
            o2 += z[q] * w2r[q][2];
        }
#pragma unroll
        for (int m = 1; m < 16; m <<= 1) {
            o0 += __shfl_xor(o0, m);
            o1 += __shfl_xor(o1, m);
            o2 += __shfl_xor(o2, m);
        }
        if ((l & 15) == 0) {
            float* op = out + (size_t)c.y * 3;
            op[0] = o0 + bz0;
            op[1] = o1 + bz1;
            op[2] = o2 + bz2;
        }
        c = cn;
        pa = pan;
        pb = pbn;
    }
}

extern "C" void kernel_launch(void* const* d_in, const int* in_sizes, int n_in,
                              void* d_out, int out_size, void* d_ws, size_t ws_size,
                              hipStream_t stream) {
    const float* x     = (const float*)d_in[0];
    const int*   ei    = (const int*)d_in[1];
    const float* W_enc = (const float*)d_in[2];
    const float* b_enc = (const float*)d_in[3];
    const float* Wg[3] = {(const float*)d_in[4], (const float*)d_in[6], (const float*)d_in[8]};
    const float* bg[3] = {(const float*)d_in[5], (const float*)d_in[7], (const float*)d_in[9]};
    const float* W_m1  = (const float*)d_in[10];
    const float* b_m1  = (const float*)d_in[11];
    const float* W_m2  = (const float*)d_in[12];
    const float* b_m2  = (const float*)d_in[13];
    float* out = (float*)d_out;

    // workspace layout (~86 MB)
    char* w = (char*)d_ws;
    ushort* hH      = (ushort*)w;  w += (size_t)N_NODES * HID * 2;       // 12.8 MB (P alias)
    ushort* hL      = (ushort*)w;  w += (size_t)N_NODES * HID * 2;       // 12.8 MB
    float*  bufA    = (float*)w;   w += (size_t)N_NODES * HID * 4;       // 25.6 MB
    float*  bufB    = (float*)w;   w += (size_t)N_NODES * HID * 4;       // 25.6 MB (Qb at end)
    int2*   csrE    = (int2*)w;    w += (size_t)N_EDGES * 8;             // 6.4 MB
    // contiguous zero-init region: cnt | cursorP | gHist
    int*    cnt     = (int*)w;     w += (size_t)N_NODES * 4;
    int*    cursorP = (int*)w;     w += (size_t)N_NODES * 4;
    int*    gHist   = (int*)w;     w += NBUCKET * 4;
    size_t  zeroBytes = (size_t)(N_NODES * 2 + NBUCKET) * 4;
    int*    rank    = (int*)w;     w += (size_t)N_NODES * 4;
    int*    invRank = (int*)w;     w += (size_t)N_NODES * 4;
    int*    rowStartP = (int*)w;   w += (size_t)(N_NODES + 4) * 4;
    float*  dinvP   = (float*)w;   w += (size_t)N_NODES * 4;
    int*    histBase = (int*)w;    w += NBUCKET * 4;
    int*    edgeBase = (int*)w;    w += NBUCKET * 4;
    int*    blockBase = (int*)w;   w += (size_t)N_NODE_BLOCKS * NBUCKET * 4;  // 0.8 MB
    ushort* WgTH[3], *WgTL[3];
    for (int i = 0; i < 3; ++i) {
        WgTH[i] = (ushort*)w; w += 128 * 128 * 2;
        WgTL[i] = (ushort*)w; w += 128 * 128 * 2;
    }
    ushort* WtTH = (ushort*)w; w += 128 * 128 * 2;
    ushort* WtTL = (ushort*)w; w += 128 * 128 * 2;
    ushort* WbTH = (ushort*)w; w += 128 * 128 * 2;
    ushort* WbTL = (ushort*)w; w += 128 * 128 * 2;

    float* P  = (float*)hH;   // 25.6 MB alias over hH+hL (unused otherwise)
    float* Qb = bufB;

    // --- degree-sorted CSR build ---
    hipMemsetAsync(cnt, 0, zeroBytes, stream);
    k_count<<<(N_EDGES + 255) / 256, 256, 0, stream>>>(ei, cnt);
    k_bhist<<<N_NODE_BLOCKS, 256, 0, stream>>>(cnt, gHist, blockBase);
    k_prefix<<<1, NBUCKET, 0, stream>>>(gHist, histBase, edgeBase, rowStartP);
    k_rank<<<N_NODE_BLOCKS, 256, 0, stream>>>(cnt, histBase, edgeBase, blockBase,
                                              rank, invRank, rowStartP, dinvP);
    k_fill<<<(N_EDGES + 255) / 256, 256, 0, stream>>>(ei, rank, rowStartP, cursorP, csrE);

    // --- all 5 weight transpose+splits in one launch ---
    WSplitArgs wa;
    wa.src[0] = Wg[0]; wa.th[0] = WgTH[0]; wa.tl[0] = WgTL[0];
    wa.src[1] = Wg[1]; wa.th[1] = WgTH[1]; wa.tl[1] = WgTL[1];
    wa.src[2] = Wg[2]; wa.th[2] = WgTH[2]; wa.tl[2] = WgTL[2];
    wa.src[3] = W_m1;             wa.th[3] = WtTH; wa.tl[3] = WtTL;
    wa.src[4] = W_m1 + 128 * 128; wa.th[4] = WbTH; wa.tl[4] = WbTL;
    k_tsplit5<<<5 * 16384 / 256, 256, 0, stream>>>(wa);

    // fused encoder + layer-1 GEMM: bufA = (relu(x@W_enc+b) @ Wg1^T) * dinvP (rank space)
    k_enc_gemm<<<N_NODES / 16, 512, 0, stream>>>(x, W_enc, b_enc, invRank, dinvP,
                                                 WgTH[0], WgTL[0], bufA);

    const int fusedGrid = (N_NODES + 63) / 64;  // 782
    k_agg_gemm<<<fusedGrid, 512, 0, stream>>>(bufA, bg[0], dinvP, rowStartP, csrE,
                                              WgTH[1], WgTL[1], nullptr, nullptr,
                                              bufB, nullptr, nullptr, dinvP);
    k_agg_gemm<<<fusedGrid, 512, 0, stream>>>(bufB, bg[1], dinvP, rowStartP, csrE,
                                              WgTH[2], WgTL[2], nullptr, nullptr,
                                              bufA, nullptr, nullptr, dinvP);
    k_agg_gemm<<<fusedGrid, 512, 0, stream>>>(bufA, bg[2], dinvP, rowStartP, csrE,
                                              WtTH, WtTL, WbTH, WbTL,
                                              P, Qb, b_m1, nullptr);

    k_edge_final<<<(N_NODES * 64) / 256, 256, 0, stream>>>(P, Qb, rowStartP, csrE,
                                                           W_m2, b_m2, out);
}

// Round 18
// 427.673 us; speedup vs baseline: 1.0398x; 1.0398x over previous
//
#include <hip/hip_runtime.h>
#include <hip/hip_bf16.h>

#define N_NODES 50000
#define N_EDGES 800000
#define HID 128
#define NBUCKET 1024
#define N_NODE_BLOCKS ((N_NODES + 255) / 256)  // 196

typedef __attribute__((ext_vector_type(8))) short bf16x8;
typedef __attribute__((ext_vector_type(4))) float f32x4;

__device__ __forceinline__ ushort f2bf(float f) {
    uint u = __float_as_uint(f);
    return (ushort)((u + 0x7FFFu + ((u >> 16) & 1u)) >> 16);  // RNE
}
__device__ __forceinline__ float bf2f(ushort h) { return __uint_as_float(((uint)h) << 16); }

// ---------------- degree count ----------------
__global__ void k_count(const int* __restrict__ ei, int* cnt) {
    int e = blockIdx.x * blockDim.x + threadIdx.x;
    if (e < N_EDGES) atomicAdd(&cnt[ei[N_EDGES + e]], 1);
}

// ---------------- counting sort by degree: per-block hist + global base ----------------
__global__ __launch_bounds__(256) void k_bhist(const int* __restrict__ cnt, int* gHist,
                                               int* __restrict__ blockBase) {
    __shared__ int lh[NBUCKET];
    int t = threadIdx.x;
    for (int d = t; d < NBUCKET; d += 256) lh[d] = 0;
    __syncthreads();
    int n = blockIdx.x * 256 + t;
    if (n < N_NODES) {
        int deg = min(cnt[n], NBUCKET - 1);
        atomicAdd(&lh[deg], 1);
    }
    __syncthreads();
    for (int d = t; d < NBUCKET; d += 256) {
        int c = lh[d];
        blockBase[blockIdx.x * NBUCKET + d] = c ? atomicAdd(&gHist[d], c) : 0;
    }
}

// exclusive prefix over gHist (node base) and gHist[d]*d (edge base)
__global__ __launch_bounds__(NBUCKET) void k_prefix(const int* __restrict__ gHist,
                                                    int* __restrict__ histBase,
                                                    int* __restrict__ edgeBase,
                                                    int* __restrict__ rowStartP) {
    __shared__ int a[NBUCKET];
    __shared__ int b[NBUCKET];
    int t = threadIdx.x;
    int h = gHist[t];
    a[t] = h;
    b[t] = h * t;
    __syncthreads();
    for (int off = 1; off < NBUCKET; off <<= 1) {
        int av = (t >= off) ? a[t - off] : 0;
        int bv = (t >= off) ? b[t - off] : 0;
        __syncthreads();
        a[t] += av;
        b[t] += bv;
        __syncthreads();
    }
    histBase[t] = a[t] - h;          // exclusive
    edgeBase[t] = b[t] - h * t;
    if (t == 0) rowStartP[N_NODES] = N_EDGES;
}

// rank[n], invRank[r], rowStartP[r] (closed form), dinvP[r]
__global__ __launch_bounds__(256) void k_rank(const int* __restrict__ cnt,
                                              const int* __restrict__ histBase,
                                              const int* __restrict__ edgeBase,
                                              const int* __restrict__ blockBase,
                                              int* __restrict__ rank,
                                              int* __restrict__ invRank,
                                              int* __restrict__ rowStartP,
                                              float* __restrict__ dinvP) {
    __shared__ int cur[NBUCKET];
    int t = threadIdx.x;
    for (int d = t; d < NBUCKET; d += 256) cur[d] = 0;
    __syncthreads();
    int n = blockIdx.x * 256 + t;
    if (n < N_NODES) {
        int deg = min(cnt[n], NBUCKET - 1);
        int slot = atomicAdd(&cur[deg], 1);
        int r = histBase[deg] + blockBase[blockIdx.x * NBUCKET + deg] + slot;
        rank[n] = r;
        invRank[r] = n;
        rowStartP[r] = edgeBase[deg] + (r - histBase[deg]) * deg;
        dinvP[r] = rsqrtf(1.0f + (float)deg);
    }
}

// csrE[pos] = {rank[src], edge_id} grouped by rank[dst]
__global__ void k_fill(const int* __restrict__ ei, const int* __restrict__ rank,
                       const int* __restrict__ rowStartP, int* cursorP,
                       int2* __restrict__ csrE) {
    int e = blockIdx.x * blockDim.x + threadIdx.x;
    if (e < N_EDGES) {
        int s = ei[e];
        int d = ei[N_EDGES + e];
        int rd = rank[d];
        int pos = rowStartP[rd] + atomicAdd(&cursorP[rd], 1);
        csrE[pos] = make_int2(rank[s], e);
    }
}

// ---------------- 5x weight transpose + bf16 hi/lo split ----------------
struct WSplitArgs {
    const float* src[5];
    ushort* th[5];
    ushort* tl[5];
};

__global__ void k_tsplit5(WSplitArgs a) {
    int i = blockIdx.x * 256 + threadIdx.x;  // 5 * 16384
    int which = i >> 14, r = i & 16383;
    int k = r >> 7, j = r & 127;
    float v = a.src[which][r];
    ushort hi = f2bf(v);
    a.th[which][j * 128 + k] = hi;
    a.tl[which][j * 128 + k] = f2bf(v - bf2f(hi));
}

// ---------------- fused encoder + layer-1 GEMM ----------------
__global__ __launch_bounds__(512, 8) void k_enc_gemm(
    const float* __restrict__ x, const float* __restrict__ Wenc,
    const float* __restrict__ benc, const int* __restrict__ invRank,
    const float* __restrict__ dinvP,
    const ushort* __restrict__ BTH, const ushort* __restrict__ BTL,
    float* __restrict__ out) {
    __shared__ uint AsH[16][68];
    __shared__ uint AsL[16][68];
    int tid = threadIdx.x;

    if (tid < 256) {
        int ln = tid >> 4, li = tid & 15;
        int r = blockIdx.x * 16 + ln;
        int n = invRank[r];
        float4 xv = *(const float4*)(x + (size_t)n * 4);
        int j0 = li * 8;
        uint uh[4], ul[4];
#pragma unroll
        for (int p = 0; p < 4; ++p) {
            ushort hs[2], ls[2];
#pragma unroll
            for (int q = 0; q < 2; ++q) {
                int j = j0 + p * 2 + q;
                float acc = benc[j];
                acc += xv.x * Wenc[0 * 128 + j];
                acc += xv.y * Wenc[1 * 128 + j];
                acc += xv.z * Wenc[2 * 128 + j];
                acc += xv.w * Wenc[3 * 128 + j];
                float v = fmaxf(acc, 0.f);
                hs[q] = f2bf(v);
                ls[q] = f2bf(v - bf2f(hs[q]));
            }
            uh[p] = (uint)hs[0] | ((uint)hs[1] << 16);
            ul[p] = (uint)ls[0] | ((uint)ls[1] << 16);
        }
        *(uint4*)&AsH[ln][li * 4] = make_uint4(uh[0], uh[1], uh[2], uh[3]);
        *(uint4*)&AsL[ln][li * 4] = make_uint4(ul[0], ul[1], ul[2], ul[3]);
    }
    __syncthreads();

    int w = tid >> 6, l = tid & 63;
    int ln = l & 15, lk = l >> 4;
    int ct = w;
    int node = blockIdx.x * 16 + ln;
    f32x4 acc = {};
#pragma unroll
    for (int kc = 0; kc < 4; ++kc) {
        uint4 uhv = *(uint4*)&AsH[ln][kc * 16 + lk * 4];
        uint4 ulv = *(uint4*)&AsL[ln][kc * 16 + lk * 4];
        bf16x8 hh, hl;
        __builtin_memcpy(&hh, &uhv, 16);
        __builtin_memcpy(&hl, &ulv, 16);
        size_t boff = (size_t)(ct * 16 + ln) * 128 + kc * 32 + lk * 8;
        bf16x8 wh = *(const bf16x8*)(BTH + boff);
        bf16x8 wl = *(const bf16x8*)(BTL + boff);
        acc = __builtin_amdgcn_mfma_f32_16x16x32_bf16(wh, hh, acc, 0, 0, 0);
        acc = __builtin_amdgcn_mfma_f32_16x16x32_bf16(wl, hh, acc, 0, 0, 0);
        acc = __builtin_amdgcn_mfma_f32_16x16x32_bf16(wh, hl, acc, 0, 0, 0);
    }
    int jb = ct * 16 + lk * 4;
    float s = dinvP[node];
    *(float4*)(out + (size_t)node * 128 + jb) =
        make_float4(acc[0] * s, acc[1] * s, acc[2] * s, acc[3] * s);
}

// ---------------- fused aggregate + GEMM (32-node tiles, degree-balanced) ----------------
// Phase A: 32 rank-consecutive nodes per block (degrees differ <=1). Each wave
// handles 4 nodes: 2 concurrently (2 groups x 16 lanes per node, full 512B row
// per group, 1-ahead prefetch) x 2 serially (degree-identical, no divergence).
// Phase B: GEMM from LDS ([32][68] padded): wave w owns col-tile ct=w, computes
// BOTH row-tiles (rows 0-15, 16-31) per weight fragment -> halved weight traffic.
__global__ __launch_bounds__(512, 8) void k_agg_gemm(
    const float* __restrict__ hw, const float* __restrict__ bg,
    const float* __restrict__ dinvP, const int* __restrict__ rowStartP,
    const int2* __restrict__ csrE,
    const ushort* __restrict__ BTH1, const ushort* __restrict__ BTL1,
    const ushort* __restrict__ BTH2, const ushort* __restrict__ BTL2,
    float* __restrict__ out1, float* __restrict__ out2,
    const float* __restrict__ b1, const float* __restrict__ outScale) {
    __shared__ uint AsH[32][68];
    __shared__ uint AsL[32][68];
    int tid = threadIdx.x;
    int w = tid >> 6, l = tid & 63;
    int sub = l >> 5;        // node within wave pair (concurrent)
    int g2 = (l >> 4) & 1;   // edge-group within node
    int li = l & 15;
    int c8 = li * 8;

    // ---- Phase A: 2 serial x 2 concurrent nodes per wave ----
#pragma unroll
    for (int q = 0; q < 2; ++q) {
        int r = w * 4 + sub * 2 + q;
        int n = blockIdx.x * 32 + r;
        if (n >= N_NODES) n = N_NODES - 1;  // tail clamp (stores guarded in phase B)
        float4 aA, aB;
        if (g2 == 0) {  // self term
            aA = *(const float4*)(hw + (size_t)n * 128 + c8);
            aB = *(const float4*)(hw + (size_t)n * 128 + c8 + 4);
        } else {
            aA = make_float4(0.f, 0.f, 0.f, 0.f);
            aB = aA;
        }
        int s0 = rowStartP[n], s1 = rowStartP[n + 1];
        int k = s0 + g2;
        float4 v0a = make_float4(0.f, 0.f, 0.f, 0.f), v0b = v0a;
        if (k < s1) {
            const float* rp = hw + (size_t)csrE[k].x * 128 + c8;
            v0a = *(const float4*)(rp);
            v0b = *(const float4*)(rp + 4);
        }
        for (; k < s1; k += 2) {
            float4 v1a = make_float4(0.f, 0.f, 0.f, 0.f), v1b = v1a;
            if (k + 2 < s1) {
                const float* rp = hw + (size_t)csrE[k + 2].x * 128 + c8;
                v1a = *(const float4*)(rp);
                v1b = *(const float4*)(rp + 4);
            }
            aA.x += v0a.x; aA.y += v0a.y; aA.z += v0a.z; aA.w += v0a.w;
            aB.x += v0b.x; aB.y += v0b.y; aB.z += v0b.z; aB.w += v0b.w;
            v0a = v1a;
            v0b = v1b;
        }
        // combine the 2 edge-groups (lanes l and l^16)
        aA.x += __shfl_xor(aA.x, 16); aA.y += __shfl_xor(aA.y, 16);
        aA.z += __shfl_xor(aA.z, 16); aA.w += __shfl_xor(aA.w, 16);
        aB.x += __shfl_xor(aB.x, 16); aB.y += __shfl_xor(aB.y, 16);
        aB.z += __shfl_xor(aB.z, 16); aB.w += __shfl_xor(aB.w, 16);

        if (g2 == 0) {
            float di = dinvP[n];
            float4 bbA = *(const float4*)(bg + c8);
            float4 bbB = *(const float4*)(bg + c8 + 4);
            float f0 = fmaxf(bbA.x + di * aA.x, 0.f);
            float f1 = fmaxf(bbA.y + di * aA.y, 0.f);
            float f2 = fmaxf(bbA.z + di * aA.z, 0.f);
            float f3 = fmaxf(bbA.w + di * aA.w, 0.f);
            float f4 = fmaxf(bbB.x + di * aB.x, 0.f);
            float f5 = fmaxf(bbB.y + di * aB.y, 0.f);
            float f6 = fmaxf(bbB.z + di * aB.z, 0.f);
            float f7 = fmaxf(bbB.w + di * aB.w, 0.f);
            ushort h0 = f2bf(f0), h1 = f2bf(f1), h2 = f2bf(f2), h3 = f2bf(f3);
            ushort h4 = f2bf(f4), h5 = f2bf(f5), h6 = f2bf(f6), h7 = f2bf(f7);
            uint4 uh = make_uint4((uint)h0 | ((uint)h1 << 16), (uint)h2 | ((uint)h3 << 16),
                                  (uint)h4 | ((uint)h5 << 16), (uint)h6 | ((uint)h7 << 16));
            ushort l0 = f2bf(f0 - bf2f(h0)), l1 = f2bf(f1 - bf2f(h1));
            ushort l2 = f2bf(f2 - bf2f(h2)), l3 = f2bf(f3 - bf2f(h3));
            ushort l4 = f2bf(f4 - bf2f(h4)), l5 = f2bf(f5 - bf2f(h5));
            ushort l6 = f2bf(f6 - bf2f(h6)), l7 = f2bf(f7 - bf2f(h7));
            uint4 ul = make_uint4((uint)l0 | ((uint)l1 << 16), (uint)l2 | ((uint)l3 << 16),
                                  (uint)l4 | ((uint)l5 << 16), (uint)l6 | ((uint)l7 << 16));
            *(uint4*)&AsH[r][li * 4] = uh;
            *(uint4*)&AsL[r][li * 4] = ul;
        }
    }
    __syncthreads();

    // ---- Phase B: GEMM from LDS. wave w owns col-tile ct=w, both row-tiles ----
    int ln = l & 15, lk = l >> 4;
    int ct = w;
    int node0 = blockIdx.x * 32 + ln;
    int node1 = blockIdx.x * 32 + 16 + ln;
    f32x4 acc1a = {}, acc1b = {};
    f32x4 acc2a = {}, acc2b = {};
#pragma unroll
    for (int kc = 0; kc < 4; ++kc) {
        uint4 uh0 = *(uint4*)&AsH[ln][kc * 16 + lk * 4];
        uint4 ul0 = *(uint4*)&AsL[ln][kc * 16 + lk * 4];
        uint4 uh1 = *(uint4*)&AsH[16 + ln][kc * 16 + lk * 4];
        uint4 ul1 = *(uint4*)&AsL[16 + ln][kc * 16 + lk * 4];
        bf16x8 hh0, hl0, hh1, hl1;
        __builtin_memcpy(&hh0, &uh0, 16);
        __builtin_memcpy(&hl0, &ul0, 16);
        __builtin_memcpy(&hh1, &uh1, 16);
        __builtin_memcpy(&hl1, &ul1, 16);
        size_t boff = (size_t)(ct * 16 + ln) * 128 + kc * 32 + lk * 8;
        bf16x8 wh = *(const bf16x8*)(BTH1 + boff);
        bf16x8 wl = *(const bf16x8*)(BTL1 + boff);
        acc1a = __builtin_amdgcn_mfma_f32_16x16x32_bf16(wh, hh0, acc1a, 0, 0, 0);
        acc1a = __builtin_amdgcn_mfma_f32_16x16x32_bf16(wl, hh0, acc1a, 0, 0, 0);
        acc1a = __builtin_amdgcn_mfma_f32_16x16x32_bf16(wh, hl0, acc1a, 0, 0, 0);
        acc1b = __builtin_amdgcn_mfma_f32_16x16x32_bf16(wh, hh1, acc1b, 0, 0, 0);
        acc1b = __builtin_amdgcn_mfma_f32_16x16x32_bf16(wl, hh1, acc1b, 0, 0, 0);
        acc1b = __builtin_amdgcn_mfma_f32_16x16x32_bf16(wh, hl1, acc1b, 0, 0, 0);
        if (BTH2) {
            bf16x8 wh2 = *(const bf16x8*)(BTH2 + boff);
            bf16x8 wl2 = *(const bf16x8*)(BTL2 + boff);
            acc2a = __builtin_amdgcn_mfma_f32_16x16x32_bf16(wh2, hh0, acc2a, 0, 0, 0);
            acc2a = __builtin_amdgcn_mfma_f32_16x16x32_bf16(wl2, hh0, acc2a, 0, 0, 0);
            acc2a = __builtin_amdgcn_mfma_f32_16x16x32_bf16(wh2, hl0, acc2a, 0, 0, 0);
            acc2b = __builtin_amdgcn_mfma_f32_16x16x32_bf16(wh2, hh1, acc2b, 0, 0, 0);
            acc2b = __builtin_amdgcn_mfma_f32_16x16x32_bf16(wl2, hh1, acc2b, 0, 0, 0);
            acc2b = __builtin_amdgcn_mfma_f32_16x16x32_bf16(wh2, hl1, acc2b, 0, 0, 0);
        }
    }
    int jb = ct * 16 + lk * 4;
    if (outScale) {
        if (node0 < N_NODES) {
            float s = outScale[node0];
            *(float4*)(out1 + (size_t)node0 * 128 + jb) =
                make_float4(acc1a[0] * s, acc1a[1] * s, acc1a[2] * s, acc1a[3] * s);
        }
        if (node1 < N_NODES) {
            float s = outScale[node1];
            *(float4*)(out1 + (size_t)node1 * 128 + jb) =
                make_float4(acc1b[0] * s, acc1b[1] * s, acc1b[2] * s, acc1b[3] * s);
        }
    } else {
        float4 bv = *(const float4*)(b1 + jb);
        if (node0 < N_NODES) {
            *(float4*)(out1 + (size_t)node0 * 128 + jb) =
                make_float4(acc1a[0], acc1a[1], acc1a[2], acc1a[3]);
            *(float4*)(out2 + (size_t)node0 * 128 + jb) =
                make_float4(acc2a[0] + bv.x, acc2a[1] + bv.y, acc2a[2] + bv.z, acc2a[3] + bv.w);
        }
        if (node1 < N_NODES) {
            *(float4*)(out1 + (size_t)node1 * 128 + jb) =
                make_float4(acc1b[0], acc1b[1], acc1b[2], acc1b[3]);
            *(float4*)(out2 + (size_t)node1 * 128 + jb) =
                make_float4(acc2b[0] + bv.x, acc2b[1] + bv.y, acc2b[2] + bv.z, acc2b[3] + bv.w);
        }
    }
}

// ---------------- edge final: out[eid] = relu(P[rs] + Qb[rd]) @ W2 + b2 ----------------
__global__ __launch_bounds__(256) void k_edge_final(const float* __restrict__ P,
                                                    const float* __restrict__ Qb,
                                                    const int* __restrict__ rowStartP,
                                                    const int2* __restrict__ csrE,
                                                    const float* __restrict__ W2,
                                                    const float* __restrict__ b2,
                                                    float* __restrict__ out) {
    int wid = (blockIdx.x * 256 + threadIdx.x) >> 6;  // one wave per dst rank
    int l = threadIdx.x & 63;
    if (wid >= N_NODES) return;
    int s0 = rowStartP[wid], s1 = rowStartP[wid + 1];
    if (s0 >= s1) return;
    int j8 = (l & 15) * 8;
    int g = l >> 4;

    float4 qa = *(const float4*)(Qb + (size_t)wid * 128 + j8);
    float4 qb = *(const float4*)(Qb + (size_t)wid * 128 + j8 + 4);
    float w2r[8][3];
#pragma unroll
    for (int k = 0; k < 8; ++k) {
        w2r[k][0] = W2[(j8 + k) * 3 + 0];
        w2r[k][1] = W2[(j8 + k) * 3 + 1];
        w2r[k][2] = W2[(j8 + k) * 3 + 2];
    }
    float bz0 = b2[0], bz1 = b2[1], bz2 = b2[2];

    int k = s0 + g;
    int2 c = make_int2(0, 0);
    float4 pa = make_float4(0.f, 0.f, 0.f, 0.f), pb = pa;
    if (k < s1) {
        c = csrE[k];
        const float* pr = P + (size_t)c.x * 128 + j8;
        pa = *(const float4*)(pr);
        pb = *(const float4*)(pr + 4);
    }
    for (; k < s1; k += 4) {
        int kn = k + 4;
        int2 cn = make_int2(0, 0);
        float4 pan = make_float4(0.f, 0.f, 0.f, 0.f), pbn = pan;
        if (kn < s1) {
            cn = csrE[kn];
            const float* prn = P + (size_t)cn.x * 128 + j8;
            pan = *(const float4*)(prn);
            pbn = *(const float4*)(prn + 4);
        }
        float z[8];
        z[0] = fmaxf(pa.x + qa.x, 0.f);
        z[1] = fmaxf(pa.y + qa.y, 0.f);
        z[2] = fmaxf(pa.z + qa.z, 0.f);
        z[3] = fmaxf(pa.w + qa.w, 0.f);
        z[4] = fmaxf(pb.x + qb.x, 0.f);
        z[5] = fmaxf(pb.y + qb.y, 0.f);
        z[6] = fmaxf(pb.z + qb.z, 0.f);
        z[7] = fmaxf(pb.w + qb.w, 0.f);
        float o0 = 0.f, o1 = 0.f, o2 = 0.f;
#pragma unroll
        for (int q = 0; q < 8; ++q) {
            o0 += z[q] * w2r[q][0];
            o1 += z[q] * w2r[q][1];
            o2 += z[q] * w2r[q][2];
        }
#pragma unroll
        for (int m = 1; m < 16; m <<= 1) {
            o0 += __shfl_xor(o0, m);
            o1 += __shfl_xor(o1, m);
            o2 += __shfl_xor(o2, m);
        }
        if ((l & 15) == 0) {
            float* op = out + (size_t)c.y * 3;
            op[0] = o0 + bz0;
            op[1] = o1 + bz1;
            op[2] = o2 + bz2;
        }
        c = cn;
        pa = pan;
        pb = pbn;
    }
}

extern "C" void kernel_launch(void* const* d_in, const int* in_sizes, int n_in,
                              void* d_out, int out_size, void* d_ws, size_t ws_size,
                              hipStream_t stream) {
    const float* x     = (const float*)d_in[0];
    const int*   ei    = (const int*)d_in[1];
    const float* W_enc = (const float*)d_in[2];
    const float* b_enc = (const float*)d_in[3];
    const float* Wg[3] = {(const float*)d_in[4], (const float*)d_in[6], (const float*)d_in[8]};
    const float* bg[3] = {(const float*)d_in[5], (const float*)d_in[7], (const float*)d_in[9]};
    const float* W_m1  = (const float*)d_in[10];
    const float* b_m1  = (const float*)d_in[11];
    const float* W_m2  = (const float*)d_in[12];
    const float* b_m2  = (const float*)d_in[13];
    float* out = (float*)d_out;

    // workspace layout (~86 MB)
    char* w = (char*)d_ws;
    ushort* hH      = (ushort*)w;  w += (size_t)N_NODES * HID * 2;       // 12.8 MB (P alias)
    ushort* hL      = (ushort*)w;  w += (size_t)N_NODES * HID * 2;       // 12.8 MB
    float*  bufA    = (float*)w;   w += (size_t)N_NODES * HID * 4;       // 25.6 MB
    float*  bufB    = (float*)w;   w += (size_t)N_NODES * HID * 4;       // 25.6 MB (Qb at end)
    int2*   csrE    = (int2*)w;    w += (size_t)N_EDGES * 8;             // 6.4 MB
    // contiguous zero-init region: cnt | cursorP | gHist
    int*    cnt     = (int*)w;     w += (size_t)N_NODES * 4;
    int*    cursorP = (int*)w;     w += (size_t)N_NODES * 4;
    int*    gHist   = (int*)w;     w += NBUCKET * 4;
    size_t  zeroBytes = (size_t)(N_NODES * 2 + NBUCKET) * 4;
    int*    rank    = (int*)w;     w += (size_t)N_NODES * 4;
    int*    invRank = (int*)w;     w += (size_t)N_NODES * 4;
    int*    rowStartP = (int*)w;   w += (size_t)(N_NODES + 4) * 4;
    float*  dinvP   = (float*)w;   w += (size_t)N_NODES * 4;
    int*    histBase = (int*)w;    w += NBUCKET * 4;
    int*    edgeBase = (int*)w;    w += NBUCKET * 4;
    int*    blockBase = (int*)w;   w += (size_t)N_NODE_BLOCKS * NBUCKET * 4;  // 0.8 MB
    ushort* WgTH[3], *WgTL[3];
    for (int i = 0; i < 3; ++i) {
        WgTH[i] = (ushort*)w; w += 128 * 128 * 2;
        WgTL[i] = (ushort*)w; w += 128 * 128 * 2;
    }
    ushort* WtTH = (ushort*)w; w += 128 * 128 * 2;
    ushort* WtTL = (ushort*)w; w += 128 * 128 * 2;
    ushort* WbTH = (ushort*)w; w += 128 * 128 * 2;
    ushort* WbTL = (ushort*)w; w += 128 * 128 * 2;

    float* P  = (float*)hH;   // 25.6 MB alias over hH+hL (unused otherwise)
    float* Qb = bufB;

    // --- degree-sorted CSR build ---
    hipMemsetAsync(cnt, 0, zeroBytes, stream);
    k_count<<<(N_EDGES + 255) / 256, 256, 0, stream>>>(ei, cnt);
    k_bhist<<<N_NODE_BLOCKS, 256, 0, stream>>>(cnt, gHist, blockBase);
    k_prefix<<<1, NBUCKET, 0, stream>>>(gHist, histBase, edgeBase, rowStartP);
    k_rank<<<N_NODE_BLOCKS, 256, 0, stream>>>(cnt, histBase, edgeBase, blockBase,
                                              rank, invRank, rowStartP, dinvP);
    k_fill<<<(N_EDGES + 255) / 256, 256, 0, stream>>>(ei, rank, rowStartP, cursorP, csrE);

    // --- all 5 weight transpose+splits in one launch ---
    WSplitArgs wa;
    wa.src[0] = Wg[0]; wa.th[0] = WgTH[0]; wa.tl[0] = WgTL[0];
    wa.src[1] = Wg[1]; wa.th[1] = WgTH[1]; wa.tl[1] = WgTL[1];
    wa.src[2] = Wg[2]; wa.th[2] = WgTH[2]; wa.tl[2] = WgTL[2];
    wa.src[3] = W_m1;             wa.th[3] = WtTH; wa.tl[3] = WtTL;
    wa.src[4] = W_m1 + 128 * 128; wa.th[4] = WbTH; wa.tl[4] = WbTL;
    k_tsplit5<<<5 * 16384 / 256, 256, 0, stream>>>(wa);

    // fused encoder + layer-1 GEMM: bufA = (relu(x@W_enc+b) @ Wg1^T) * dinvP (rank space)
    k_enc_gemm<<<N_NODES / 16, 512, 0, stream>>>(x, W_enc, b_enc, invRank, dinvP,
                                                 WgTH[0], WgTL[0], bufA);

    const int fusedGrid = (N_NODES + 31) / 32;  // 1563
    k_agg_gemm<<<fusedGrid, 512, 0, stream>>>(bufA, bg[0], dinvP, rowStartP, csrE,
                                              WgTH[1], WgTL[1], nullptr, nullptr,
                                              bufB, nullptr, nullptr, dinvP);
    k_agg_gemm<<<fusedGrid, 512, 0, stream>>>(bufB, bg[1], dinvP, rowStartP, csrE,
                                              WgTH[2], WgTL[2], nullptr, nullptr,
                                              bufA, nullptr, nullptr, dinvP);
    k_agg_gemm<<<fusedGrid, 512, 0, stream>>>(bufA, bg[2], dinvP, rowStartP, csrE,
                                              WtTH, WtTL, WbTH, WbTL,
                                              P, Qb, b_m1, nullptr);

    k_edge_final<<<(N_NODES * 64) / 256, 256, 0, stream>>>(P, Qb, rowStartP, csrE,
                                                           W_m2, b_m2, out);
}